// Round 13
// baseline (5798.362 us; speedup 1.0000x reference)
//
#include <hip/hip_runtime.h>

typedef unsigned short u16;
typedef unsigned int u32;
typedef unsigned long long u64;
typedef __attribute__((ext_vector_type(8))) short bf16x8;   // 8 bf16 = 4 VGPRs
typedef __attribute__((ext_vector_type(4))) float f32x4;
typedef __attribute__((ext_vector_type(4))) u32 u32x4;

namespace {
constexpr int kT = 1024, kI = 64, kH = 512, kO = 24;
constexpr int kBH = 64 * kH;                  // 32768 elems per h buffer (bf16)
constexpr int kNWG = 100;                     // 32 L1 + 64 L2 + 4 OUT
// RING-8: h1 8 bufs @0, h2 8 bufs @512KB (buf = k&7), tags k mod 3 (unique
// mod 24; skew <= 8 via throttle). bufs 3,6 invalid-init (first tick b has
// b%3==0 == zero-init tag -- R8-class hazard).
constexpr unsigned kBarOff = 16u * (unsigned)kBH * 2u;  // 1048576 B
// ctl ints: [0..63] flagL2[j2] (j2 = ub2*4+g), [64..67] flagOUT[g]
}

__device__ __forceinline__ u16 f2bf(float f) {   // round-to-nearest-even
  union { float f; u32 u; } c; c.f = f;
  u32 u = c.u + 0x7FFFu + ((c.u >> 16) & 1u);
  return (u16)(u >> 16);
}
__device__ __forceinline__ float sigf(float x) { return 1.0f / (1.0f + __expf(-x)); }
__device__ __forceinline__ float tanhf_(float x) {
  float e = __expf(2.0f * x); return 1.0f - 2.0f / (e + 1.0f);  // safe at +-inf
}
__device__ __forceinline__ bf16x8 cvt8(const float* p) {  // fp32x8 -> bf16x8 (RNE)
  const float4 f0 = *reinterpret_cast<const float4*>(p);
  const float4 f1 = *reinterpret_cast<const float4*>(p + 4);
  bf16x8 r;
  r[0] = (short)f2bf(f0.x); r[1] = (short)f2bf(f0.y);
  r[2] = (short)f2bf(f0.z); r[3] = (short)f2bf(f0.w);
  r[4] = (short)f2bf(f1.x); r[5] = (short)f2bf(f1.y);
  r[6] = (short)f2bf(f1.z); r[7] = (short)f2bf(f1.w);
  return r;
}
__device__ __forceinline__ f32x4 mfma(bf16x8 a, bf16x8 b, f32x4 c) {
  return __builtin_amdgcn_mfma_f32_16x16x32_bf16(a, b, c, 0, 0, 0);
}
__device__ __forceinline__ int ldflag(const int* s, int i) {
  return __hip_atomic_load(&s[i], __ATOMIC_RELAXED, __HIP_MEMORY_SCOPE_AGENT);
}
__device__ __forceinline__ void stflag(int* s, int i, int v) {
  __hip_atomic_store(&s[i], v, __ATOMIC_RELAXED, __HIP_MEMORY_SCOPE_AGENT);
}
// PIPELINED agent fetch (R5-proven): all loads in one asm block, sc0 sc1,
// ONE vmcnt drain => ~1 round trip per handshake.
union V16 { u32x4 u; bf16x8 v; };
__device__ __forceinline__ void fetch4(const u16* p, bf16x8* ch) {
  u32x4 a, b, c, d;
  asm volatile(
    "global_load_dwordx4 %0, %4, off sc0 sc1\n\t"
    "global_load_dwordx4 %1, %4, off offset:64 sc0 sc1\n\t"
    "global_load_dwordx4 %2, %4, off offset:128 sc0 sc1\n\t"
    "global_load_dwordx4 %3, %4, off offset:192 sc0 sc1\n\t"
    "s_waitcnt vmcnt(0)"
    : "=&v"(a), "=&v"(b), "=&v"(c), "=&v"(d) : "v"(p) : "memory");
  V16 t;
  t.u = a; ch[0] = t.v;  t.u = b; ch[1] = t.v;
  t.u = c; ch[2] = t.v;  t.u = d; ch[3] = t.v;
}
__device__ __forceinline__ void fetch8(const u16* p, bf16x8* ch) {
  u32x4 a, b, c, d, e, f, g2, h;
  asm volatile(
    "global_load_dwordx4 %0, %8, off sc0 sc1\n\t"
    "global_load_dwordx4 %1, %8, off offset:64 sc0 sc1\n\t"
    "global_load_dwordx4 %2, %8, off offset:128 sc0 sc1\n\t"
    "global_load_dwordx4 %3, %8, off offset:192 sc0 sc1\n\t"
    "global_load_dwordx4 %4, %8, off offset:256 sc0 sc1\n\t"
    "global_load_dwordx4 %5, %8, off offset:320 sc0 sc1\n\t"
    "global_load_dwordx4 %6, %8, off offset:384 sc0 sc1\n\t"
    "global_load_dwordx4 %7, %8, off offset:448 sc0 sc1\n\t"
    "s_waitcnt vmcnt(0)"
    : "=&v"(a), "=&v"(b), "=&v"(c), "=&v"(d),
      "=&v"(e), "=&v"(f), "=&v"(g2), "=&v"(h) : "v"(p) : "memory");
  V16 t;
  t.u = a; ch[0] = t.v;  t.u = b;  ch[1] = t.v;
  t.u = c; ch[2] = t.v;  t.u = d;  ch[3] = t.v;
  t.u = e; ch[4] = t.v;  t.u = f;  ch[5] = t.v;
  t.u = g2; ch[6] = t.v; t.u = h;  ch[7] = t.v;
}
// 16-chunk fetch (R6-proven): full 512-col h row-slab for 16 batches,
// 16 loads + ONE vmcnt drain.
__device__ __forceinline__ void fetch16(const u16* p, bf16x8* ch) {
  u32x4 t0,t1,t2,t3,t4,t5,t6,t7,t8,t9,t10,t11,t12,t13,t14,t15;
  asm volatile(
    "global_load_dwordx4 %0, %16, off sc0 sc1\n\t"
    "global_load_dwordx4 %1, %16, off offset:64 sc0 sc1\n\t"
    "global_load_dwordx4 %2, %16, off offset:128 sc0 sc1\n\t"
    "global_load_dwordx4 %3, %16, off offset:192 sc0 sc1\n\t"
    "global_load_dwordx4 %4, %16, off offset:256 sc0 sc1\n\t"
    "global_load_dwordx4 %5, %16, off offset:320 sc0 sc1\n\t"
    "global_load_dwordx4 %6, %16, off offset:384 sc0 sc1\n\t"
    "global_load_dwordx4 %7, %16, off offset:448 sc0 sc1\n\t"
    "global_load_dwordx4 %8, %16, off offset:512 sc0 sc1\n\t"
    "global_load_dwordx4 %9, %16, off offset:576 sc0 sc1\n\t"
    "global_load_dwordx4 %10, %16, off offset:640 sc0 sc1\n\t"
    "global_load_dwordx4 %11, %16, off offset:704 sc0 sc1\n\t"
    "global_load_dwordx4 %12, %16, off offset:768 sc0 sc1\n\t"
    "global_load_dwordx4 %13, %16, off offset:832 sc0 sc1\n\t"
    "global_load_dwordx4 %14, %16, off offset:896 sc0 sc1\n\t"
    "global_load_dwordx4 %15, %16, off offset:960 sc0 sc1\n\t"
    "s_waitcnt vmcnt(0)"
    : "=&v"(t0), "=&v"(t1), "=&v"(t2), "=&v"(t3),
      "=&v"(t4), "=&v"(t5), "=&v"(t6), "=&v"(t7),
      "=&v"(t8), "=&v"(t9), "=&v"(t10), "=&v"(t11),
      "=&v"(t12), "=&v"(t13), "=&v"(t14), "=&v"(t15)
    : "v"(p) : "memory");
  V16 u;
  u.u=t0; ch[0]=u.v;   u.u=t1; ch[1]=u.v;   u.u=t2; ch[2]=u.v;   u.u=t3; ch[3]=u.v;
  u.u=t4; ch[4]=u.v;   u.u=t5; ch[5]=u.v;   u.u=t6; ch[6]=u.v;   u.u=t7; ch[7]=u.v;
  u.u=t8; ch[8]=u.v;   u.u=t9; ch[9]=u.v;   u.u=t10; ch[10]=u.v; u.u=t11; ch[11]=u.v;
  u.u=t12; ch[12]=u.v; u.u=t13; ch[13]=u.v; u.u=t14; ch[14]=u.v; u.u=t15; ch[15]=u.v;
}
// tick tag (k mod 3) in LSBs of bf16 elems 0,1 of each 8B granule.
__device__ __forceinline__ u32 pat3(int t3) {
  return ((u32)t3 & 1u) | ((((u32)t3 >> 1) & 1u) << 16);
}
template<int N>
__device__ __forceinline__ bool tagsok(const bf16x8* ch, u32 pat) {
  bool ok = true;
#pragma unroll
  for (int c = 0; c < N; ++c) {
    union { bf16x8 v; u32 u[4]; } t; t.v = ch[c];
    ok = ok && ((t.u[0] & 0x10001u) == pat) && ((t.u[2] & 0x10001u) == pat);
  }
  return ok;
}
// sentinel poll (R6-proven): one 8B agent load per lane; 64 lanes span the
// 32 producer tiles x 2 batch extremes of the group slab. Gates fat fetch.
__device__ __forceinline__ void pollh(const u16* ps, u32 pat) {
  int sp = 0;
  for (;;) {
    u64 g = __hip_atomic_load((const u64*)ps, __ATOMIC_RELAXED, __HIP_MEMORY_SCOPE_AGENT);
    if (__all(((u32)g & 0x10001u) == pat)) break;
    if ((++sp & 7) == 7) __builtin_amdgcn_s_sleep(1);
  }
}
__device__ __forceinline__ void fetchv16(const u16* p, u32 pat, bf16x8* ch) {
  int sp = 0;
  for (;;) {
    fetch16(p, ch);
    if (__all(tagsok<16>(ch, pat))) break;
    if ((++sp & 7) == 7) __builtin_amdgcn_s_sleep(1);
  }
  __asm__ volatile("" ::: "memory");
}
// POLL-FIRST tagged wait (R7/R10-proven; optimistic variant refuted R9/R11)
template<int N>
__device__ __forceinline__ void dataD(const u16* p, u32 pat, bf16x8* ch) {
  int spins = 0;
  for (;;) {
    u64 g0 = __hip_atomic_load((const u64*)p, __ATOMIC_RELAXED, __HIP_MEMORY_SCOPE_AGENT);
    if (__all(((u32)g0 & 0x10001u) == pat)) break;
    if ((++spins & 3) == 3) __builtin_amdgcn_s_sleep(1);
  }
  spins = 0;
  for (;;) {
    if constexpr (N == 4) fetch4(p, ch); else fetch8(p, ch);
    if (__all(tagsok<N>(ch, pat))) break;
    if ((++spins & 7) == 7) __builtin_amdgcn_s_sleep(1);
  }
  __asm__ volatile("" ::: "memory");
}
// tagged h store: 4 bf16 + 2 tag bits, ONE agent-scope atomic 8B store
__device__ __forceinline__ void st_h(u16* p, const float* h, int t3) {
  u16 a = (u16)((f2bf(h[0]) & ~1u) | ((u32)t3 & 1u));
  u16 b = (u16)((f2bf(h[1]) & ~1u) | (((u32)t3 >> 1) & 1u));
  u64 v = (u64)a | ((u64)b << 16) | ((u64)f2bf(h[2]) << 32) | ((u64)f2bf(h[3]) << 48);
  __hip_atomic_store((u64*)p, v, __ATOMIC_RELAXED, __HIP_MEMORY_SCOPE_AGENT);
}
// RING-8 GRADED throttle (R10-proven): banks the real consumer position =>
// polls ~once per 7 ticks. Gate flag >= k-7 before overwriting tick k-8.
__device__ __forceinline__ void throttle8(const int* f, int idx, bool act,
                                          int k, int& bound) {
  if (bound >= k - 7) return;
  for (;;) {
    int v = act ? ldflag(f, idx) : 0x7fffffff;
    if (__all(v >= k - 7)) {
      bound = __all(v >= k - 1) ? (k - 1) : (__all(v >= k - 4) ? (k - 4) : (k - 7));
      break;
    }
    __builtin_amdgcn_s_sleep(2);
  }
}

// R13 == R12 resubmitted verbatim (R12 bench was a container-level infra
// failure, no data; deadlock/bounds/resource audits found no kernel defect).
// R12 = R10 base (poll-first, ring-8 graded throttle, distributed act in L2)
// with L1 REPLACED by the R6-proven barrier-free per-wave stage: each of
// 128 L1 waves owns a (16-unit x 16-batch) tile, full K=512 whh1 resident
// (192 VGPR), fetch16 slab read, 54 MFMA, lane-local activation, st_h.
// NO barriers, NO LDS on the recurrence chain -- removes 2 rendezvous +
// 2 vmcnt drains + LDS exchange (~1us) from the serial tick.
//   wg  0..31 : L1. wave idx=wg*4+w: ut=idx&31 (16-unit tile), g=idx>>5.
//   wg 32..95 : L2. ub2 (32-unit block), g. 4 waves = quarters of combined
//               K=1024: kh0,1 = wih2@h1[k]; kh2,3 = whh2@h2[k-1].
//   wg 96..99 : OUT. g3 group. 4 waves = mat x K-half. fin=mat0,kh0.
// Certification (transitive, R10-proven): flagL2[all 16 of g] >= k-7 =>
// L2 fetch-verified h1[k-7] => every L1 peer stored k-7 => peers at tick
// >= k-6 read bufs (k-7..k-1)&7, distinct from k&7. Same for h2 via flagOUT.
// L1 peer self-cert: full-slab tag-verify of h1[k-1] => all peers at tick
// >= k => peers read bufs >= (k-2)&7, never k-8.
// MFMA 16x16x32: A=weights m=unit(l15), B=h n=batch(l15), C/D col=l15(batch),
// row=q*4+r(unit) -> activations lane-local.
__global__ __launch_bounds__(256, 1) void stackgru(
    const float* __restrict__ x,
    const float* __restrict__ wih1, const float* __restrict__ whh1,
    const float* __restrict__ bih1, const float* __restrict__ bhh1,
    const float* __restrict__ wih2, const float* __restrict__ whh2,
    const float* __restrict__ bih2, const float* __restrict__ bhh2,
    const float* __restrict__ wo1, const float* __restrict__ bo1,
    const float* __restrict__ wo2, const float* __restrict__ bo2,
    float* __restrict__ out, u16* __restrict__ hbuf, int* __restrict__ ctl)
{
  __shared__ float red[4][3][4][64][4];   // 48 KB: [kh][gate][m][lane][r]
  __shared__ float sbias[4][64];          // staged biases (L2)
  const int wg = blockIdx.x;
  const int tid = threadIdx.x;
  const int lane = tid & 63;
  const int w = tid >> 6;                 // wave 0..3
  const int l15 = lane & 15;
  const int q = lane >> 4;

  u16* h1b = hbuf;                        // 8 * kBH
  u16* h2b = hbuf + 8 * kBH;              // 8 * kBH

  if (wg < 32) {
    // ---------------- layer 1 (barrier-free per-wave tiles) ----------------
    const int idx = wg * 4 + w;           // 0..127
    const int ut = idx & 31, U0 = ut * 16;
    const int g = idx >> 5;               // batch group 0..3
    const int bb = g * 16 + l15;
    bf16x8 whf[3][16];                    // 192 VGPR resident w_hh1 (K=512)
#pragma unroll
    for (int gg = 0; gg < 3; ++gg)
#pragma unroll
      for (int c = 0; c < 16; ++c)
        whf[gg][c] = cvt8(whh1 + (size_t)(gg * kH + U0 + l15) * kH + c * 32 + q * 8);
    bf16x8 aihf[3][2];                    // 24 VGPR w_ih1 (K=64)
#pragma unroll
    for (int gg = 0; gg < 3; ++gg)
#pragma unroll
      for (int c = 0; c < 2; ++c)
        aihf[gg][c] = cvt8(wih1 + (size_t)(gg * kH + U0 + l15) * kI + c * 32 + q * 8);
    float br[4], bz[4], bni[4], bnh[4], h1l[4];
#pragma unroll
    for (int r = 0; r < 4; ++r) {
      int u = U0 + q * 4 + r;
      br[r]  = bih1[u]          + bhh1[u];
      bz[r]  = bih1[kH + u]     + bhh1[kH + u];
      bni[r] = bih1[2 * kH + u];
      bnh[r] = bhh1[2 * kH + u];
      h1l[r] = 0.0f;
    }
    // sentinel: lane -> producer tile (lane&31), batch rows 0/15 of group
    const int sU = (lane & 31) * 16;
    const int sB = (lane >> 5) * 15;
    // throttle watch: lanes 0..15 flagL2[lane*4+g], lane 16 flagOUT[g]
    const int thridx = (lane < 16) ? (lane * 4 + g) : (64 + g);
    const bool thract = (lane < 17);
    int bound = 0;
    for (int k = 1; k <= kT; ++k) {
      const int t3 = k % 3, t3p = (k - 1) % 3;
      const float* xs = x + ((size_t)bb * kT + (k - 1)) * kI + q * 8;
      bf16x8 xf0 = cvt8(xs), xf1 = cvt8(xs + 32);
      const u16* pb = h1b + ((k - 1) & 7) * kBH;
      pollh(pb + (size_t)(g * 16 + sB) * kH + sU, pat3(t3p));
      bf16x8 ch[16];
      fetchv16(pb + (size_t)bb * kH + q * 8, pat3(t3p), ch);
      f32x4 aR = {0,0,0,0}, aZ = {0,0,0,0}, aNh = {0,0,0,0}, aNi = {0,0,0,0};
#pragma unroll
      for (int c = 0; c < 16; ++c) {
        aR  = mfma(whf[0][c], ch[c], aR);
        aZ  = mfma(whf[1][c], ch[c], aZ);
        aNh = mfma(whf[2][c], ch[c], aNh);
      }
      aR  = mfma(aihf[0][0], xf0, aR);  aR  = mfma(aihf[0][1], xf1, aR);
      aZ  = mfma(aihf[1][0], xf0, aZ);  aZ  = mfma(aihf[1][1], xf1, aZ);
      aNi = mfma(aihf[2][0], xf0, aNi); aNi = mfma(aihf[2][1], xf1, aNi);
      throttle8(ctl, thridx, thract, k, bound);   // h1 anti-dep (ring-8)
      float hnew[4];
#pragma unroll
      for (int r = 0; r < 4; ++r) {
        float rr = sigf(aR[r] + br[r]);
        float zz = sigf(aZ[r] + bz[r]);
        float nn = tanhf_(aNi[r] + bni[r] + rr * (aNh[r] + bnh[r]));
        float h  = (1.0f - zz) * nn + zz * h1l[r];
        h1l[r] = h; hnew[r] = h;
      }
      st_h(h1b + (k & 7) * kBH + (size_t)bb * kH + U0 + q * 4, hnew, t3);
    }
  } else if (wg < 96) {
    // ---------------- layer 2 (combined K=1024 GEMM) == R10 ----------------
    const int j2 = wg - 32;
    const int ub2 = j2 >> 2, g = j2 & 3;
    const int U0 = ub2 * 32;
    const int bb = g * 16 + l15;
    const int kh = w;                     // 0,1: wih2 halves; 2,3: whh2 halves
    const float* src = (kh < 2) ? wih2 : whh2;
    const int koff = (kh & 1) * 256;      // K-offset within the 512-dim matrix
    bf16x8 whf[3][2][8];                  // 192 VGPR resident weights
#pragma unroll
    for (int gg = 0; gg < 3; ++gg)
#pragma unroll
      for (int m = 0; m < 2; ++m)
#pragma unroll
        for (int c = 0; c < 8; ++c)
          whf[gg][m][c] = cvt8(src + (size_t)(gg * kH + U0 + m * 16 + l15) * kH
                               + koff + c * 32 + q * 8);
    if (tid < 32) {                       // stage biases once
      int u = U0 + tid;
      sbias[0][tid] = bih2[u]          + bhh2[u];
      sbias[1][tid] = bih2[kH + u]     + bhh2[kH + u];
      sbias[2][tid] = bih2[2 * kH + u];
      sbias[3][tid] = bhh2[2 * kH + u];
    }
    float h2l[4];                         // wave w<2 uses (unit-block m=w)
#pragma unroll
    for (int r = 0; r < 4; ++r) h2l[r] = 0.0f;
    __syncthreads();
    int bound = 0;
    for (int k = 1; k <= kT; ++k) {
      const int t3 = k % 3, t3p = (k - 1) % 3;
      const u16* base; u32 pat;
      if (kh < 2) { base = h1b + (k & 7) * kBH;       pat = pat3(t3);  }
      else        { base = h2b + ((k - 1) & 7) * kBH; pat = pat3(t3p); }
      bf16x8 ch[8];
      dataD<8>(base + (size_t)bb * kH + koff + q * 8, pat, ch);
      f32x4 a[3][2];
#pragma unroll
      for (int gg = 0; gg < 3; ++gg)
#pragma unroll
        for (int m = 0; m < 2; ++m) a[gg][m] = {0,0,0,0};
#pragma unroll
      for (int m = 0; m < 2; ++m)
#pragma unroll
        for (int c = 0; c < 8; ++c) {
          a[0][m] = mfma(whf[0][m][c], ch[c], a[0][m]);
          a[1][m] = mfma(whf[1][m][c], ch[c], a[1][m]);
          a[2][m] = mfma(whf[2][m][c], ch[c], a[2][m]);
        }
#pragma unroll
      for (int gg = 0; gg < 3; ++gg)
#pragma unroll
        for (int m = 0; m < 2; ++m)
#pragma unroll
          for (int r = 0; r < 4; ++r) red[kh][gg][m][lane][r] = a[gg][m][r];
      if (kh == 0) throttle8(ctl, 64 + g, lane < 1, k, bound);  // h2 anti-dep
      __syncthreads();
      if (tid == 0) stflag(ctl, j2, k);   // all 4 waves fetch-verified tick k
      if (w < 2) {                        // distributed act: wave m = w
        const int m = w;
        float hnew[4];
#pragma unroll
        for (int r = 0; r < 4; ++r) {
          float gi0 = red[0][0][m][lane][r] + red[1][0][m][lane][r];
          float gi1 = red[0][1][m][lane][r] + red[1][1][m][lane][r];
          float gi2 = red[0][2][m][lane][r] + red[1][2][m][lane][r];
          float gh0 = red[2][0][m][lane][r] + red[3][0][m][lane][r];
          float gh1 = red[2][1][m][lane][r] + red[3][1][m][lane][r];
          float gh2 = red[2][2][m][lane][r] + red[3][2][m][lane][r];
          int uu = m * 16 + q * 4 + r;
          float rr = sigf(gi0 + gh0 + sbias[0][uu]);
          float zz = sigf(gi1 + gh1 + sbias[1][uu]);
          float nn = tanhf_(gi2 + sbias[2][uu] + rr * (gh2 + sbias[3][uu]));
          float h  = (1.0f - zz) * nn + zz * h2l[r];
          h2l[r] = h; hnew[r] = h;
        }
        st_h(h2b + (k & 7) * kBH + (size_t)bb * kH + U0 + m * 16 + q * 4, hnew, t3);
      }
      __syncthreads();                    // guards red reuse
    }
  } else {
    // ---------------- output head == R10 ----------------
    const int g3 = wg - 96;
    const int bb = g3 * 16 + l15;
    const int mat = w & 1, khh = w >> 1;  // matrix x K-half
    const float* wsel = mat ? wo2 : wo1;
    bf16x8 zf = {0,0,0,0,0,0,0,0};
    bf16x8 wof[2][8];
#pragma unroll
    for (int t = 0; t < 2; ++t)
#pragma unroll
      for (int c = 0; c < 8; ++c) {
        int row = t * 16 + l15;
        wof[t][c] = (row < kO) ? cvt8(wsel + (size_t)row * kH + khh * 256 + c * 32 + q * 8) : zf;
      }
    float bv1[2][4], bv2[2][4];
#pragma unroll
    for (int t = 0; t < 2; ++t)
#pragma unroll
      for (int r = 0; r < 4; ++r) {
        int o = t * 16 + q * 4 + r;
        bv1[t][r] = (o < kO) ? bo1[o] : 0.0f;
        bv2[t][r] = (o < kO) ? bo2[o] : 0.0f;
      }
    const bool fin = (mat == 0 && khh == 0);
    const u16* slab = mat ? h2b : h1b;
    for (int k = 1; k <= kT; ++k) {
      const u32 pat = pat3(k % 3);
      bf16x8 ch[8];
      dataD<8>(slab + (k & 7) * kBH + (size_t)bb * kH + khh * 256 + q * 8, pat, ch);
      f32x4 a0 = {0,0,0,0}, a1 = {0,0,0,0};
#pragma unroll
      for (int c = 0; c < 8; ++c) {
        a0 = mfma(wof[0][c], ch[c], a0);
        a1 = mfma(wof[1][c], ch[c], a1);
      }
      if (!fin) {
        const int s = mat * 2 + khh - 1;  // (0,1)->0 (1,0)->1 (1,1)->2
#pragma unroll
        for (int r = 0; r < 4; ++r) {
          red[s][0][0][lane][r] = a0[r];
          red[s][0][1][lane][r] = a1[r];
        }
      }
      __syncthreads();
      if (tid == 0) stflag(ctl, 64 + g3, k);   // h1[k] & h2[k] fetch-verified
      if (fin) {
#pragma unroll
        for (int t = 0; t < 2; ++t) {
          int o0 = t * 16 + q * 4;
          if (o0 < kO) {
            f32x4 av = (t == 0) ? a0 : a1;
            float4 ov;
            ov.x = tanhf_(av[0] + red[0][0][t][lane][0] + bv1[t][0]) +
                   tanhf_(red[1][0][t][lane][0] + red[2][0][t][lane][0] + bv2[t][0]);
            ov.y = tanhf_(av[1] + red[0][0][t][lane][1] + bv1[t][1]) +
                   tanhf_(red[1][0][t][lane][1] + red[2][0][t][lane][1] + bv2[t][1]);
            ov.z = tanhf_(av[2] + red[0][0][t][lane][2] + bv1[t][2]) +
                   tanhf_(red[1][0][t][lane][2] + red[2][0][t][lane][2] + bv2[t][2]);
            ov.w = tanhf_(av[3] + red[0][0][t][lane][3] + bv1[t][3]) +
                   tanhf_(red[1][0][t][lane][3] + red[2][0][t][lane][3] + bv2[t][3]);
            *reinterpret_cast<float4*>(out + ((size_t)bb * kT + (k - 1)) * kO + o0) = ov;
          }
        }
      }
      __syncthreads();                    // guards red reuse
    }
  }
}

extern "C" void kernel_launch(void* const* d_in, const int* in_sizes, int n_in,
                              void* d_out, int out_size, void* d_ws, size_t ws_size,
                              hipStream_t stream) {
  (void)in_sizes; (void)n_in; (void)out_size; (void)ws_size;
  // zero h rings + control page; invalid-tag init for bufs 3,6 of h1 & h2
  // (first occupant tick b has b%3==0 == zero-init tag -- R8-class hazard)
  hipMemsetAsync(d_ws, 0, kBarOff + 1024, stream);
  hipMemsetAsync((char*)d_ws + 3u * kBH * 2u, 0x01, kBH * 2u, stream);              // h1 buf3
  hipMemsetAsync((char*)d_ws + 6u * kBH * 2u, 0x01, kBH * 2u, stream);              // h1 buf6
  hipMemsetAsync((char*)d_ws + (8u + 3u) * kBH * 2u, 0x01, kBH * 2u, stream);       // h2 buf3
  hipMemsetAsync((char*)d_ws + (8u + 6u) * kBH * 2u, 0x01, kBH * 2u, stream);       // h2 buf6
  const float* x    = (const float*)d_in[0];
  const float* wih1 = (const float*)d_in[1];
  const float* whh1 = (const float*)d_in[2];
  const float* bih1 = (const float*)d_in[3];
  const float* bhh1 = (const float*)d_in[4];
  const float* wih2 = (const float*)d_in[5];
  const float* whh2 = (const float*)d_in[6];
  const float* bih2 = (const float*)d_in[7];
  const float* bhh2 = (const float*)d_in[8];
  const float* wo1  = (const float*)d_in[9];
  const float* bo1  = (const float*)d_in[10];
  const float* wo2  = (const float*)d_in[11];
  const float* bo2  = (const float*)d_in[12];
  float* out  = (float*)d_out;
  u16* hbuf   = (u16*)d_ws;
  int* ctl    = (int*)((char*)d_ws + kBarOff);
  stackgru<<<dim3(kNWG), dim3(256), 0, stream>>>(
      x, wih1, whh1, bih1, bhh1, wih2, whh2, bih2, bhh2,
      wo1, bo1, wo2, bo2, out, hbuf, ctl);
}

// Round 14
// 3562.000 us; speedup vs baseline: 1.6278x; 1.6278x over previous
//
#include <hip/hip_runtime.h>

typedef unsigned short u16;
typedef unsigned int u32;
typedef unsigned long long u64;
typedef __attribute__((ext_vector_type(8))) short bf16x8;   // 8 bf16 = 4 VGPRs
typedef __attribute__((ext_vector_type(4))) float f32x4;
typedef __attribute__((ext_vector_type(4))) u32 u32x4;

namespace {
constexpr int kT = 1024, kI = 64, kH = 512, kO = 24;
constexpr int kBH = 64 * kH;                  // 32768 elems per h buffer (bf16)
constexpr int kNWG = 100;                     // 32 L1 + 64 L2 + 4 OUT
// RING-8: h1 8 bufs @0, h2 8 bufs @512KB (buf = k&7), tags k mod 3 (unique
// mod 24; skew <= 8 via throttle). bufs 3,6 invalid-init (first tick b has
// b%3==0 == zero-init tag -- R8-class hazard).
constexpr unsigned kBarOff = 16u * (unsigned)kBH * 2u;  // 1048576 B
// ctl ints: [0..63] flagL2[j2] (j2 = ub2*4+g), [64..67] flagOUT[g]
}

__device__ __forceinline__ u16 f2bf(float f) {   // round-to-nearest-even
  union { float f; u32 u; } c; c.f = f;
  u32 u = c.u + 0x7FFFu + ((c.u >> 16) & 1u);
  return (u16)(u >> 16);
}
__device__ __forceinline__ float sigf(float x) { return 1.0f / (1.0f + __expf(-x)); }
__device__ __forceinline__ float tanhf_(float x) {
  float e = __expf(2.0f * x); return 1.0f - 2.0f / (e + 1.0f);  // safe at +-inf
}
__device__ __forceinline__ bf16x8 cvt8(const float* p) {  // fp32x8 -> bf16x8 (RNE)
  const float4 f0 = *reinterpret_cast<const float4*>(p);
  const float4 f1 = *reinterpret_cast<const float4*>(p + 4);
  bf16x8 r;
  r[0] = (short)f2bf(f0.x); r[1] = (short)f2bf(f0.y);
  r[2] = (short)f2bf(f0.z); r[3] = (short)f2bf(f0.w);
  r[4] = (short)f2bf(f1.x); r[5] = (short)f2bf(f1.y);
  r[6] = (short)f2bf(f1.z); r[7] = (short)f2bf(f1.w);
  return r;
}
__device__ __forceinline__ f32x4 mfma(bf16x8 a, bf16x8 b, f32x4 c) {
  return __builtin_amdgcn_mfma_f32_16x16x32_bf16(a, b, c, 0, 0, 0);
}
__device__ __forceinline__ int ldflag(const int* s, int i) {
  return __hip_atomic_load(&s[i], __ATOMIC_RELAXED, __HIP_MEMORY_SCOPE_AGENT);
}
__device__ __forceinline__ void stflag(int* s, int i, int v) {
  __hip_atomic_store(&s[i], v, __ATOMIC_RELAXED, __HIP_MEMORY_SCOPE_AGENT);
}
// LDS-only barrier (R14 single-variable test): __syncthreads drains vmcnt(0),
// serializing the st_h ack RT into every tick. Barrier 2 only guards LDS
// (red) reuse -- the ack drain moves into the NEXT tick's fetch vmcnt(0),
// overlapped with the load RT. (R11 bundled this with the refuted optimistic
// fetch; never isolated until now.)
__device__ __forceinline__ void barrier_lds() {
  asm volatile("s_waitcnt lgkmcnt(0)" ::: "memory");
  __builtin_amdgcn_s_barrier();
}
// PIPELINED agent fetch (R5-proven): all loads in one asm block, sc0 sc1,
// ONE vmcnt drain => ~1 round trip per handshake. The vmcnt(0) also absorbs
// this wave's outstanding st_h ack (overlapped, not serialized).
union V16 { u32x4 u; bf16x8 v; };
__device__ __forceinline__ void fetch4(const u16* p, bf16x8* ch) {
  u32x4 a, b, c, d;
  asm volatile(
    "global_load_dwordx4 %0, %4, off sc0 sc1\n\t"
    "global_load_dwordx4 %1, %4, off offset:64 sc0 sc1\n\t"
    "global_load_dwordx4 %2, %4, off offset:128 sc0 sc1\n\t"
    "global_load_dwordx4 %3, %4, off offset:192 sc0 sc1\n\t"
    "s_waitcnt vmcnt(0)"
    : "=&v"(a), "=&v"(b), "=&v"(c), "=&v"(d) : "v"(p) : "memory");
  V16 t;
  t.u = a; ch[0] = t.v;  t.u = b; ch[1] = t.v;
  t.u = c; ch[2] = t.v;  t.u = d; ch[3] = t.v;
}
__device__ __forceinline__ void fetch8(const u16* p, bf16x8* ch) {
  u32x4 a, b, c, d, e, f, g2, h;
  asm volatile(
    "global_load_dwordx4 %0, %8, off sc0 sc1\n\t"
    "global_load_dwordx4 %1, %8, off offset:64 sc0 sc1\n\t"
    "global_load_dwordx4 %2, %8, off offset:128 sc0 sc1\n\t"
    "global_load_dwordx4 %3, %8, off offset:192 sc0 sc1\n\t"
    "global_load_dwordx4 %4, %8, off offset:256 sc0 sc1\n\t"
    "global_load_dwordx4 %5, %8, off offset:320 sc0 sc1\n\t"
    "global_load_dwordx4 %6, %8, off offset:384 sc0 sc1\n\t"
    "global_load_dwordx4 %7, %8, off offset:448 sc0 sc1\n\t"
    "s_waitcnt vmcnt(0)"
    : "=&v"(a), "=&v"(b), "=&v"(c), "=&v"(d),
      "=&v"(e), "=&v"(f), "=&v"(g2), "=&v"(h) : "v"(p) : "memory");
  V16 t;
  t.u = a; ch[0] = t.v;  t.u = b;  ch[1] = t.v;
  t.u = c; ch[2] = t.v;  t.u = d;  ch[3] = t.v;
  t.u = e; ch[4] = t.v;  t.u = f;  ch[5] = t.v;
  t.u = g2; ch[6] = t.v; t.u = h;  ch[7] = t.v;
}
// tick tag (k mod 3) in LSBs of bf16 elems 0,1 of each 8B granule.
__device__ __forceinline__ u32 pat3(int t3) {
  return ((u32)t3 & 1u) | ((((u32)t3 >> 1) & 1u) << 16);
}
template<int N>
__device__ __forceinline__ bool tagsok(const bf16x8* ch, u32 pat) {
  bool ok = true;
#pragma unroll
  for (int c = 0; c < N; ++c) {
    union { bf16x8 v; u32 u[4]; } t; t.v = ch[c];
    ok = ok && ((t.u[0] & 0x10001u) == pat) && ((t.u[2] & 0x10001u) == pat);
  }
  return ok;
}
// POLL-FIRST tagged wait (R7/R10-proven; optimistic variant refuted
// R9/R11): phase 1 polls each lane's first 8B granule (cheap), phase 2
// pipelined fetch + full tag verify (~1 iter).
template<int N>
__device__ __forceinline__ void dataD(const u16* p, u32 pat, bf16x8* ch) {
  int spins = 0;
  for (;;) {
    u64 g0 = __hip_atomic_load((const u64*)p, __ATOMIC_RELAXED, __HIP_MEMORY_SCOPE_AGENT);
    if (__all(((u32)g0 & 0x10001u) == pat)) break;
    if ((++spins & 3) == 3) __builtin_amdgcn_s_sleep(1);
  }
  spins = 0;
  for (;;) {
    if constexpr (N == 4) fetch4(p, ch); else fetch8(p, ch);
    if (__all(tagsok<N>(ch, pat))) break;
    if ((++spins & 7) == 7) __builtin_amdgcn_s_sleep(1);
  }
  __asm__ volatile("" ::: "memory");
}
// tagged h store: 4 bf16 + 2 tag bits, ONE agent-scope atomic 8B store
__device__ __forceinline__ void st_h(u16* p, const float* h, int t3) {
  u16 a = (u16)((f2bf(h[0]) & ~1u) | ((u32)t3 & 1u));
  u16 b = (u16)((f2bf(h[1]) & ~1u) | (((u32)t3 >> 1) & 1u));
  u64 v = (u64)a | ((u64)b << 16) | ((u64)f2bf(h[2]) << 32) | ((u64)f2bf(h[3]) << 48);
  __hip_atomic_store((u64*)p, v, __ATOMIC_RELAXED, __HIP_MEMORY_SCOPE_AGENT);
}
// RING-8 GRADED throttle (R10-proven): banks the real consumer position =>
// polls ~once per 7 ticks. Gate flag >= k-7 before overwriting tick k-8.
__device__ __forceinline__ void throttle8(const int* f, int idx, bool act,
                                          int k, int& bound) {
  if (bound >= k - 7) return;
  for (;;) {
    int v = act ? ldflag(f, idx) : 0x7fffffff;
    if (__all(v >= k - 7)) {
      bound = __all(v >= k - 1) ? (k - 1) : (__all(v >= k - 4) ? (k - 4) : (k - 7));
      break;
    }
    __builtin_amdgcn_s_sleep(2);
  }
}

// R14 == R10 (best: 3553/3485 steady) + ONE change: the per-tick second
// barrier is lgkmcnt-only (barrier_lds) in all three roles. Everything else
// (poll-first dataD, ring-8 graded throttle, distributed activation,
// narrow per-wave K-quarter dependencies) is byte-identical to R10.
// R12/R13's barrier-free L1 is REVERTED (4x fetch volume + 32-producer
// sentinel gate cost more than two barriers -- narrow deps win).
//   wg  0..31 : L1. ub=wg>>2 (64-unit block), g=wg&3. 4 waves = K-quarters;
//               x-GEMM (K=64) on kh1/kh2, n-gate x-partial via LDS redx.
//   wg 32..95 : L2. ub2 (32-unit block), g. 4 waves = quarters of combined
//               K=1024: kh0,1 = wih2@h1[k]; kh2,3 = whh2@h2[k-1].
//   wg 96..99 : OUT. g3 group. 4 waves = mat x K-half. fin=mat0,kh0.
// flagL2[j2]/flagOUT[g] post after barrier 1 (all fetches tag-verified).
// MFMA 16x16x32: A=weights m=unit(l15), B=h n=batch(l15), C/D col=l15(batch),
// row=q*4+r(unit) -> activations lane-local.
__global__ __launch_bounds__(256, 1) void stackgru(
    const float* __restrict__ x,
    const float* __restrict__ wih1, const float* __restrict__ whh1,
    const float* __restrict__ bih1, const float* __restrict__ bhh1,
    const float* __restrict__ wih2, const float* __restrict__ whh2,
    const float* __restrict__ bih2, const float* __restrict__ bhh2,
    const float* __restrict__ wo1, const float* __restrict__ bo1,
    const float* __restrict__ wo2, const float* __restrict__ bo2,
    float* __restrict__ out, u16* __restrict__ hbuf, int* __restrict__ ctl)
{
  __shared__ float red[4][3][4][64][4];   // 48 KB: [kh][gate][m][lane][r]
  __shared__ float redx[2][4][64][4];     // 8 KB: x n-gate partials (L1)
  __shared__ float sbias[4][64];          // staged biases
  const int wg = blockIdx.x;
  const int tid = threadIdx.x;
  const int lane = tid & 63;
  const int w = tid >> 6;                 // wave 0..3
  const int l15 = lane & 15;
  const int q = lane >> 4;

  u16* h1b = hbuf;                        // 8 * kBH
  u16* h2b = hbuf + 8 * kBH;              // 8 * kBH

  if (wg < 32) {
    // ---------------- layer 1 ----------------
    const int ub = wg >> 2, g = wg & 3;
    const int U0 = ub * 64;
    const int bb = g * 16 + l15;
    const int kh = w;                     // K-quarter (0..3), 128 K each
    bf16x8 whf[3][4][4];                  // 192 VGPR resident w_hh1
#pragma unroll
    for (int gg = 0; gg < 3; ++gg)
#pragma unroll
      for (int m = 0; m < 4; ++m)
#pragma unroll
        for (int c = 0; c < 4; ++c)
          whf[gg][m][c] = cvt8(whh1 + (size_t)(gg * kH + U0 + m * 16 + l15) * kH
                               + (kh * 4 + c) * 32 + q * 8);
    const bool hasx = (kh == 1 || kh == 2);
    const int xch = kh - 1;               // x chunk 0/1 (K=64 total)
    bf16x8 aihf[3][4];                    // 48 VGPR (kh1/kh2 only)
    if (hasx)
#pragma unroll
      for (int gg = 0; gg < 3; ++gg)
#pragma unroll
        for (int m = 0; m < 4; ++m)
          aihf[gg][m] = cvt8(wih1 + (size_t)(gg * kH + U0 + m * 16 + l15) * kI
                             + xch * 32 + q * 8);
    if (tid < 64) {                       // stage biases once
      int u = U0 + tid;
      sbias[0][tid] = bih1[u]          + bhh1[u];
      sbias[1][tid] = bih1[kH + u]     + bhh1[kH + u];
      sbias[2][tid] = bih1[2 * kH + u];
      sbias[3][tid] = bhh1[2 * kH + u];
    }
    float h1l[4];                         // this wave's unit-block (m = w)
#pragma unroll
    for (int r = 0; r < 4; ++r) h1l[r] = 0.0f;
    __syncthreads();
    // throttle watch (kh0): lanes 0..15 = flagL2 of group, lane 16 = flagOUT
    const int thridx = (lane < 16) ? (lane * 4 + g) : (64 + g);
    const bool thract = (lane < 17);
    int bound = 0;
    for (int k = 1; k <= kT; ++k) {
      const int t3 = k % 3, t3p = (k - 1) % 3;
      bf16x8 xf;
      if (hasx)
        xf = cvt8(x + ((size_t)bb * kT + (k - 1)) * kI + xch * 32 + q * 8);
      bf16x8 ch[4];
      dataD<4>(h1b + ((k - 1) & 7) * kBH + (size_t)bb * kH + kh * 128 + q * 8,
               pat3(t3p), ch);
      f32x4 aR[4], aZ[4], aN[4];
#pragma unroll
      for (int m = 0; m < 4; ++m) { aR[m] = {0,0,0,0}; aZ[m] = {0,0,0,0}; aN[m] = {0,0,0,0}; }
#pragma unroll
      for (int m = 0; m < 4; ++m)
#pragma unroll
        for (int c = 0; c < 4; ++c) {
          aR[m] = mfma(whf[0][m][c], ch[c], aR[m]);
          aZ[m] = mfma(whf[1][m][c], ch[c], aZ[m]);
          aN[m] = mfma(whf[2][m][c], ch[c], aN[m]);
        }
      if (hasx) {
        f32x4 xN[4];
#pragma unroll
        for (int m = 0; m < 4; ++m) xN[m] = {0,0,0,0};
#pragma unroll
        for (int m = 0; m < 4; ++m) {
          aR[m] = mfma(aihf[0][m], xf, aR[m]);   // r,z: fold x into h-accum
          aZ[m] = mfma(aihf[1][m], xf, aZ[m]);
          xN[m] = mfma(aihf[2][m], xf, xN[m]);   // n_i must stay separate
        }
#pragma unroll
        for (int m = 0; m < 4; ++m)
#pragma unroll
          for (int r = 0; r < 4; ++r) redx[xch][m][lane][r] = xN[m][r];
      }
#pragma unroll
      for (int m = 0; m < 4; ++m)
#pragma unroll
        for (int r = 0; r < 4; ++r) {
          red[kh][0][m][lane][r] = aR[m][r];
          red[kh][1][m][lane][r] = aZ[m][r];
          red[kh][2][m][lane][r] = aN[m][r];
        }
      if (kh == 0) throttle8(ctl, thridx, thract, k, bound);   // h1 anti-dep
      __syncthreads();
      {                                   // distributed act: wave handles m=w
        float hnew[4];
#pragma unroll
        for (int r = 0; r < 4; ++r) {
          float sR = red[0][0][w][lane][r] + red[1][0][w][lane][r]
                   + red[2][0][w][lane][r] + red[3][0][w][lane][r];
          float sZ = red[0][1][w][lane][r] + red[1][1][w][lane][r]
                   + red[2][1][w][lane][r] + red[3][1][w][lane][r];
          float sN = red[0][2][w][lane][r] + red[1][2][w][lane][r]
                   + red[2][2][w][lane][r] + red[3][2][w][lane][r];
          float sNi = redx[0][w][lane][r] + redx[1][w][lane][r];
          int uu = w * 16 + q * 4 + r;
          float rr = sigf(sR + sbias[0][uu]);
          float zz = sigf(sZ + sbias[1][uu]);
          float nn = tanhf_(sNi + sbias[2][uu] + rr * (sN + sbias[3][uu]));
          float h  = (1.0f - zz) * nn + zz * h1l[r];
          h1l[r] = h; hnew[r] = h;
        }
        st_h(h1b + (k & 7) * kBH + (size_t)bb * kH + U0 + w * 16 + q * 4, hnew, t3);
      }
      barrier_lds();                      // guards red/redx reuse (no drain)
    }
  } else if (wg < 96) {
    // ---------------- layer 2 (combined K=1024 GEMM) ----------------
    const int j2 = wg - 32;
    const int ub2 = j2 >> 2, g = j2 & 3;
    const int U0 = ub2 * 32;
    const int bb = g * 16 + l15;
    const int kh = w;                     // 0,1: wih2 halves; 2,3: whh2 halves
    const float* src = (kh < 2) ? wih2 : whh2;
    const int koff = (kh & 1) * 256;      // K-offset within the 512-dim matrix
    bf16x8 whf[3][2][8];                  // 192 VGPR resident weights
#pragma unroll
    for (int gg = 0; gg < 3; ++gg)
#pragma unroll
      for (int m = 0; m < 2; ++m)
#pragma unroll
        for (int c = 0; c < 8; ++c)
          whf[gg][m][c] = cvt8(src + (size_t)(gg * kH + U0 + m * 16 + l15) * kH
                               + koff + c * 32 + q * 8);
    if (tid < 32) {                       // stage biases once
      int u = U0 + tid;
      sbias[0][tid] = bih2[u]          + bhh2[u];
      sbias[1][tid] = bih2[kH + u]     + bhh2[kH + u];
      sbias[2][tid] = bih2[2 * kH + u];
      sbias[3][tid] = bhh2[2 * kH + u];
    }
    float h2l[4];                         // wave w<2 uses (unit-block m=w)
#pragma unroll
    for (int r = 0; r < 4; ++r) h2l[r] = 0.0f;
    __syncthreads();
    int bound = 0;
    for (int k = 1; k <= kT; ++k) {
      const int t3 = k % 3, t3p = (k - 1) % 3;
      const u16* base; u32 pat;
      if (kh < 2) { base = h1b + (k & 7) * kBH;       pat = pat3(t3);  }
      else        { base = h2b + ((k - 1) & 7) * kBH; pat = pat3(t3p); }
      bf16x8 ch[8];
      dataD<8>(base + (size_t)bb * kH + koff + q * 8, pat, ch);
      f32x4 a[3][2];
#pragma unroll
      for (int gg = 0; gg < 3; ++gg)
#pragma unroll
        for (int m = 0; m < 2; ++m) a[gg][m] = {0,0,0,0};
#pragma unroll
      for (int m = 0; m < 2; ++m)
#pragma unroll
        for (int c = 0; c < 8; ++c) {
          a[0][m] = mfma(whf[0][m][c], ch[c], a[0][m]);
          a[1][m] = mfma(whf[1][m][c], ch[c], a[1][m]);
          a[2][m] = mfma(whf[2][m][c], ch[c], a[2][m]);
        }
#pragma unroll
      for (int gg = 0; gg < 3; ++gg)
#pragma unroll
        for (int m = 0; m < 2; ++m)
#pragma unroll
          for (int r = 0; r < 4; ++r) red[kh][gg][m][lane][r] = a[gg][m][r];
      if (kh == 0) throttle8(ctl, 64 + g, lane < 1, k, bound);  // h2 anti-dep
      __syncthreads();
      if (tid == 0) stflag(ctl, j2, k);   // all 4 waves fetch-verified tick k
      if (w < 2) {                        // distributed act: wave m = w
        const int m = w;
        float hnew[4];
#pragma unroll
        for (int r = 0; r < 4; ++r) {
          float gi0 = red[0][0][m][lane][r] + red[1][0][m][lane][r];
          float gi1 = red[0][1][m][lane][r] + red[1][1][m][lane][r];
          float gi2 = red[0][2][m][lane][r] + red[1][2][m][lane][r];
          float gh0 = red[2][0][m][lane][r] + red[3][0][m][lane][r];
          float gh1 = red[2][1][m][lane][r] + red[3][1][m][lane][r];
          float gh2 = red[2][2][m][lane][r] + red[3][2][m][lane][r];
          int uu = m * 16 + q * 4 + r;
          float rr = sigf(gi0 + gh0 + sbias[0][uu]);
          float zz = sigf(gi1 + gh1 + sbias[1][uu]);
          float nn = tanhf_(gi2 + sbias[2][uu] + rr * (gh2 + sbias[3][uu]));
          float h  = (1.0f - zz) * nn + zz * h2l[r];
          h2l[r] = h; hnew[r] = h;
        }
        st_h(h2b + (k & 7) * kBH + (size_t)bb * kH + U0 + m * 16 + q * 4, hnew, t3);
      }
      barrier_lds();                      // guards red reuse (no drain)
    }
  } else {
    // ---------------- output head ----------------
    const int g3 = wg - 96;
    const int bb = g3 * 16 + l15;
    const int mat = w & 1, khh = w >> 1;  // matrix x K-half
    const float* wsel = mat ? wo2 : wo1;
    bf16x8 zf = {0,0,0,0,0,0,0,0};
    bf16x8 wof[2][8];
#pragma unroll
    for (int t = 0; t < 2; ++t)
#pragma unroll
      for (int c = 0; c < 8; ++c) {
        int row = t * 16 + l15;
        wof[t][c] = (row < kO) ? cvt8(wsel + (size_t)row * kH + khh * 256 + c * 32 + q * 8) : zf;
      }
    float bv1[2][4], bv2[2][4];
#pragma unroll
    for (int t = 0; t < 2; ++t)
#pragma unroll
      for (int r = 0; r < 4; ++r) {
        int o = t * 16 + q * 4 + r;
        bv1[t][r] = (o < kO) ? bo1[o] : 0.0f;
        bv2[t][r] = (o < kO) ? bo2[o] : 0.0f;
      }
    const bool fin = (mat == 0 && khh == 0);
    const u16* slab = mat ? h2b : h1b;
    for (int k = 1; k <= kT; ++k) {
      const u32 pat = pat3(k % 3);
      bf16x8 ch[8];
      dataD<8>(slab + (k & 7) * kBH + (size_t)bb * kH + khh * 256 + q * 8, pat, ch);
      f32x4 a0 = {0,0,0,0}, a1 = {0,0,0,0};
#pragma unroll
      for (int c = 0; c < 8; ++c) {
        a0 = mfma(wof[0][c], ch[c], a0);
        a1 = mfma(wof[1][c], ch[c], a1);
      }
      if (!fin) {
        const int s = mat * 2 + khh - 1;  // (0,1)->0 (1,0)->1 (1,1)->2
#pragma unroll
        for (int r = 0; r < 4; ++r) {
          red[s][0][0][lane][r] = a0[r];
          red[s][0][1][lane][r] = a1[r];
        }
      }
      __syncthreads();
      if (tid == 0) stflag(ctl, 64 + g3, k);   // h1[k] & h2[k] fetch-verified
      if (fin) {
#pragma unroll
        for (int t = 0; t < 2; ++t) {
          int o0 = t * 16 + q * 4;
          if (o0 < kO) {
            f32x4 av = (t == 0) ? a0 : a1;
            float4 ov;
            ov.x = tanhf_(av[0] + red[0][0][t][lane][0] + bv1[t][0]) +
                   tanhf_(red[1][0][t][lane][0] + red[2][0][t][lane][0] + bv2[t][0]);
            ov.y = tanhf_(av[1] + red[0][0][t][lane][1] + bv1[t][1]) +
                   tanhf_(red[1][0][t][lane][1] + red[2][0][t][lane][1] + bv2[t][1]);
            ov.z = tanhf_(av[2] + red[0][0][t][lane][2] + bv1[t][2]) +
                   tanhf_(red[1][0][t][lane][2] + red[2][0][t][lane][2] + bv2[t][2]);
            ov.w = tanhf_(av[3] + red[0][0][t][lane][3] + bv1[t][3]) +
                   tanhf_(red[1][0][t][lane][3] + red[2][0][t][lane][3] + bv2[t][3]);
            *reinterpret_cast<float4*>(out + ((size_t)bb * kT + (k - 1)) * kO + o0) = ov;
          }
        }
      }
      barrier_lds();                      // guards red reuse (no drain)
    }
  }
}

extern "C" void kernel_launch(void* const* d_in, const int* in_sizes, int n_in,
                              void* d_out, int out_size, void* d_ws, size_t ws_size,
                              hipStream_t stream) {
  (void)in_sizes; (void)n_in; (void)out_size; (void)ws_size;
  // zero h rings + control page; invalid-tag init for bufs 3,6 of h1 & h2
  // (first occupant tick b has b%3==0 == zero-init tag -- R8-class hazard)
  hipMemsetAsync(d_ws, 0, kBarOff + 1024, stream);
  hipMemsetAsync((char*)d_ws + 3u * kBH * 2u, 0x01, kBH * 2u, stream);              // h1 buf3
  hipMemsetAsync((char*)d_ws + 6u * kBH * 2u, 0x01, kBH * 2u, stream);              // h1 buf6
  hipMemsetAsync((char*)d_ws + (8u + 3u) * kBH * 2u, 0x01, kBH * 2u, stream);       // h2 buf3
  hipMemsetAsync((char*)d_ws + (8u + 6u) * kBH * 2u, 0x01, kBH * 2u, stream);       // h2 buf6
  const float* x    = (const float*)d_in[0];
  const float* wih1 = (const float*)d_in[1];
  const float* whh1 = (const float*)d_in[2];
  const float* bih1 = (const float*)d_in[3];
  const float* bhh1 = (const float*)d_in[4];
  const float* wih2 = (const float*)d_in[5];
  const float* whh2 = (const float*)d_in[6];
  const float* bih2 = (const float*)d_in[7];
  const float* bhh2 = (const float*)d_in[8];
  const float* wo1  = (const float*)d_in[9];
  const float* bo1  = (const float*)d_in[10];
  const float* wo2  = (const float*)d_in[11];
  const float* bo2  = (const float*)d_in[12];
  float* out  = (float*)d_out;
  u16* hbuf   = (u16*)d_ws;
  int* ctl    = (int*)((char*)d_ws + kBarOff);
  stackgru<<<dim3(kNWG), dim3(256), 0, stream>>>(
      x, wih1, whh1, bih1, bhh1, wih2, whh2, bih2, bhh2,
      wo1, bo1, wo2, bo2, out, hbuf, ctl);
}